// Round 2
// baseline (572.238 us; speedup 1.0000x reference)
//
#include <hip/hip_runtime.h>
#include <stdint.h>

#define MTOT  16384   // B*S
#define KDIM  4096    // INTER
#define NDIM  1024    // HID
#define CLIPV 2.5f
#define BK    64
#define NSTEP (KDIM / BK)   // 64

typedef __attribute__((ext_vector_type(4)))  int i32x4;
typedef __attribute__((ext_vector_type(16))) int i32x16;
typedef __attribute__((address_space(3))) void lvoid;
typedef __attribute__((address_space(1))) void gvoid;

#define G2L16(g, l) __builtin_amdgcn_global_load_lds((gvoid*)(g), (lvoid*)(l), 16, 0, 0)

// ---------------- max|x| reduction ------------------------------------------------
__global__ __launch_bounds__(256) void maxabs_kernel(
    const float4* __restrict__ x, int n4, unsigned* __restrict__ slot) {
  __shared__ float red[4];
  float m = 0.f;
  const int stride = gridDim.x * blockDim.x;
  for (int i = blockIdx.x * blockDim.x + threadIdx.x; i < n4; i += stride) {
    float4 v = x[i];
    m = fmaxf(m, fmaxf(fmaxf(fabsf(v.x), fabsf(v.y)),
                       fmaxf(fabsf(v.z), fabsf(v.w))));
    if (__any(m >= CLIPV)) break;   // exact: result is CLIP regardless of the rest
  }
  m = fminf(m, CLIPV);
#pragma unroll
  for (int off = 32; off > 0; off >>= 1) m = fmaxf(m, __shfl_xor(m, off));
  if ((threadIdx.x & 63) == 0) red[threadIdx.x >> 6] = m;
  __syncthreads();
  if (threadIdx.x == 0) {
    float bm = fmaxf(fmaxf(red[0], red[1]), fmaxf(red[2], red[3]));
    atomicMax(slot, __float_as_uint(bm));
  }
}

// ---------------- symmetric int8 quantization: q = rint(clip(x)*127/m) ------------
// 64 B in / 16 B out per thread per iteration (uint4 stores).
__global__ __launch_bounds__(256) void quant_kernel(
    const float4* __restrict__ x, uint4* __restrict__ q, int n16,
    const unsigned* __restrict__ slot) {
  const float m = fminf(__uint_as_float(*slot), CLIPV);  // m = min(maxabs, clip)
  const float s = 127.0f / m;
  const int stride = gridDim.x * blockDim.x;
  for (int i = blockIdx.x * blockDim.x + threadIdx.x; i < n16; i += stride) {
    const float4* xp = x + 4 * (long)i;
    uint4 o;
    unsigned* op = (unsigned*)&o;
#pragma unroll
    for (int j = 0; j < 4; ++j) {
      float4 v = xp[j];
      int a = (int)rintf(fminf(fmaxf(v.x, -CLIPV), CLIPV) * s);
      int b = (int)rintf(fminf(fmaxf(v.y, -CLIPV), CLIPV) * s);
      int c = (int)rintf(fminf(fmaxf(v.z, -CLIPV), CLIPV) * s);
      int d = (int)rintf(fminf(fmaxf(v.w, -CLIPV), CLIPV) * s);
      op[j] = (unsigned)(a & 255) | ((unsigned)(b & 255) << 8) |
              ((unsigned)(c & 255) << 16) | ((unsigned)(d & 255) << 24);
    }
    q[i] = o;
  }
}

// ---------------- int8 GEMM: C[m][n] = S * sum_k qA[m][k]*qB[n][k] -----------------
// Block tile 128x256, BK=64, DOUBLE-BUFFERED LDS (2 x 24 KB, 2 blocks/CU).
// T3+T4 pipeline: per K-step issue next tile's 6 global_load_lds, then
// s_waitcnt vmcnt(6) (current tile landed, next stays in flight) + raw s_barrier.
// Never drains vmcnt to 0 inside the loop.
// LDS 16B slots swizzled within each 64B row: data(row,c) at slot c^((row>>1)&3).
//   addr/16 mod 8 = 4*(row&1) + (c^((row>>1)&3)) is a bijection over row mod 8
//   -> 8 consecutive rows cover all 8 bank-slot positions (conflict-free like the
//   proven BK=128 row&7 scheme; plain c^(row&3) would make rows r and r+4 collide).
// Epilogue fuses bias + residual add (removes 64 MB from ln_kernel).
__global__ __launch_bounds__(256, 2) void gemm_i8(
    const int8_t* __restrict__ qA, const int8_t* __restrict__ qB,
    float* __restrict__ out, const float* __restrict__ resid,
    const float* __restrict__ bias,
    const unsigned* __restrict__ slot_x, const unsigned* __restrict__ slot_w) {
  __shared__ __align__(16) int8_t As[2][128 * BK];   // 2 x 8 KB
  __shared__ __align__(16) int8_t Bs[2][256 * BK];   // 2 x 16 KB

  const int t  = threadIdx.x;
  const int l  = t & 63;
  const int w  = t >> 6;
  const int wm = (w & 1) * 64;    // wave m-offset
  const int wn = (w >> 1) * 128;  // wave n-offset
  const int lr = l & 31;          // m/n index within 32-tile
  const int lh = l >> 5;          // k-chunk half

  const long m0 = (long)blockIdx.y * 128;
  const long n0 = (long)blockIdx.x * 256;

  i32x16 acc[2][4] = {};

  // staging pointers: slot s=(t+256j) covers row=s>>2, stored col=s&3
  //   -> data col (s&3)^((row>>1)&3)
  const int8_t* gA[2];
  const int8_t* gB[4];
#pragma unroll
  for (int j = 0; j < 2; ++j) {
    const int s = t + 256 * j, row = s >> 2, cc = (s & 3) ^ ((row >> 1) & 3);
    gA[j] = qA + (m0 + row) * KDIM + cc * 16;
  }
#pragma unroll
  for (int j = 0; j < 4; ++j) {
    const int s = t + 256 * j, row = s >> 2, cc = (s & 3) ^ ((row >> 1) & 3);
    gB[j] = qB + (n0 + row) * KDIM + cc * 16;
  }
  const int ldsb = (t & 192) * 16;  // wave-uniform part of LDS dest (+ j*4096)

  // fragment address prep (per-lane): addr = base + ((c ^ mask)*16), c = kk*2+lh
  int abase[2], amask[2], bbase[4], bmask[4];
#pragma unroll
  for (int mt = 0; mt < 2; ++mt) {
    const int ra = wm + mt * 32 + lr;
    abase[mt] = ra * BK; amask[mt] = (ra >> 1) & 3;
  }
#pragma unroll
  for (int nt = 0; nt < 4; ++nt) {
    const int rb = wn + nt * 32 + lr;
    bbase[nt] = rb * BK; bmask[nt] = (rb >> 1) & 3;
  }

#define STAGE(buf, koff)                                      \
  do {                                                        \
    _Pragma("unroll")                                         \
    for (int j = 0; j < 2; ++j)                               \
      G2L16(gA[j] + (koff), &As[buf][ldsb + j * 4096]);       \
    _Pragma("unroll")                                         \
    for (int j = 0; j < 4; ++j)                               \
      G2L16(gB[j] + (koff), &Bs[buf][ldsb + j * 4096]);       \
  } while (0)

  STAGE(0, 0);   // prologue: tile 0 in flight (6 vm ops)

#pragma unroll 2
  for (int ks = 0; ks < NSTEP; ++ks) {
    const int cur = ks & 1;
    if (ks + 1 < NSTEP) {
      STAGE(cur ^ 1, (ks + 1) * BK);                     // +6 vm ops (next tile)
      asm volatile("s_waitcnt vmcnt(6)" ::: "memory");   // tile ks landed; next in flight
    } else {
      asm volatile("s_waitcnt vmcnt(0)" ::: "memory");   // last tile: drain
    }
    __builtin_amdgcn_s_barrier();                        // all waves: buf[cur] ready
    asm volatile("" ::: "memory");

    const int8_t* A_ = As[cur];
    const int8_t* B_ = Bs[cur];
#pragma unroll
    for (int kk = 0; kk < 2; ++kk) {
      const int c = kk * 2 + lh;
      i32x4 a0 = *(const i32x4*)(A_ + abase[0] + ((c ^ amask[0]) << 4));
      i32x4 a1 = *(const i32x4*)(A_ + abase[1] + ((c ^ amask[1]) << 4));
      i32x4 b0 = *(const i32x4*)(B_ + bbase[0] + ((c ^ bmask[0]) << 4));
      i32x4 b1 = *(const i32x4*)(B_ + bbase[1] + ((c ^ bmask[1]) << 4));
      i32x4 b2 = *(const i32x4*)(B_ + bbase[2] + ((c ^ bmask[2]) << 4));
      i32x4 b3 = *(const i32x4*)(B_ + bbase[3] + ((c ^ bmask[3]) << 4));
      acc[0][0] = __builtin_amdgcn_mfma_i32_32x32x32_i8(a0, b0, acc[0][0], 0, 0, 0);
      acc[1][0] = __builtin_amdgcn_mfma_i32_32x32x32_i8(a1, b0, acc[1][0], 0, 0, 0);
      acc[0][1] = __builtin_amdgcn_mfma_i32_32x32x32_i8(a0, b1, acc[0][1], 0, 0, 0);
      acc[1][1] = __builtin_amdgcn_mfma_i32_32x32x32_i8(a1, b1, acc[1][1], 0, 0, 0);
      acc[0][2] = __builtin_amdgcn_mfma_i32_32x32x32_i8(a0, b2, acc[0][2], 0, 0, 0);
      acc[1][2] = __builtin_amdgcn_mfma_i32_32x32x32_i8(a1, b2, acc[1][2], 0, 0, 0);
      acc[0][3] = __builtin_amdgcn_mfma_i32_32x32x32_i8(a0, b3, acc[0][3], 0, 0, 0);
      acc[1][3] = __builtin_amdgcn_mfma_i32_32x32x32_i8(a1, b3, acc[1][3], 0, 0, 0);
    }
    asm volatile("s_waitcnt lgkmcnt(0)" ::: "memory");   // all ds_reads of buf[cur] done
    __builtin_amdgcn_s_barrier();                        // safe to overwrite buf[cur]
    asm volatile("" ::: "memory");
  }
#undef STAGE

  const float mx = fminf(__uint_as_float(*slot_x), CLIPV);
  const float mw = fminf(__uint_as_float(*slot_w), CLIPV);
  const float S  = mx * mw * (1.0f / (127.0f * 127.0f));

  // C/D layout (32x32, dtype-independent): col=lane&31, row=(r&3)+8*(r>>2)+4*(lane>>5)
  const int coln = (int)n0 + wn + lr;
  float bv[4];
#pragma unroll
  for (int nt = 0; nt < 4; ++nt) bv[nt] = bias[coln + nt * 32];

#pragma unroll
  for (int mt = 0; mt < 2; ++mt)
#pragma unroll
    for (int r = 0; r < 16; ++r) {
      const long row = m0 + wm + mt * 32 + (r & 3) + 8 * (r >> 2) + 4 * lh;
      float* orow = out + row * NDIM + coln;
      const float* rrow = resid + row * NDIM + coln;
#pragma unroll
      for (int nt = 0; nt < 4; ++nt)
        orow[nt * 32] = (float)acc[mt][nt][r] * S + bv[nt] + rrow[nt * 32];
    }
}

// ---------------- LayerNorm (in-place on y = h + b + resid) ------------------------
// One wave per row; each lane covers 4 float4s (lane + 64*j -> 1024 floats/row).
// No LDS, no __syncthreads.
__global__ __launch_bounds__(256) void ln_kernel(
    float* __restrict__ h, const float* __restrict__ gamma,
    const float* __restrict__ beta) {
  const int lane = threadIdx.x & 63;
  const long row = (long)blockIdx.x * 4 + (threadIdx.x >> 6);
  float4* hp = (float4*)(h + row * NDIM);
  float4 y[4];
  float sum = 0.f, ss = 0.f;
#pragma unroll
  for (int j = 0; j < 4; ++j) {
    y[j] = hp[lane + 64 * j];
    sum += y[j].x + y[j].y + y[j].z + y[j].w;
    ss  += y[j].x * y[j].x + y[j].y * y[j].y + y[j].z * y[j].z + y[j].w * y[j].w;
  }
#pragma unroll
  for (int off = 32; off > 0; off >>= 1) {
    sum += __shfl_xor(sum, off);
    ss  += __shfl_xor(ss, off);
  }
  const float mu   = sum * (1.0f / NDIM);
  const float var  = ss * (1.0f / NDIM) - mu * mu;
  const float rstd = rsqrtf(var + 1e-12f);
#pragma unroll
  for (int j = 0; j < 4; ++j) {
    float4 g  = ((const float4*)gamma)[lane + 64 * j];
    float4 be = ((const float4*)beta)[lane + 64 * j];
    float4 o;
    o.x = g.x * (y[j].x - mu) * rstd + be.x;
    o.y = g.y * (y[j].y - mu) * rstd + be.y;
    o.z = g.z * (y[j].z - mu) * rstd + be.z;
    o.w = g.w * (y[j].w - mu) * rstd + be.w;
    hp[lane + 64 * j] = o;
  }
}

extern "C" void kernel_launch(void* const* d_in, const int* in_sizes, int n_in,
                              void* d_out, int out_size, void* d_ws,
                              size_t ws_size, hipStream_t stream) {
  const float* x     = (const float*)d_in[0];  // hidden_states [4,4096,4096]
  const float* resid = (const float*)d_in[1];  // input_tensor  [4,4096,1024]
  const float* W     = (const float*)d_in[2];  // [1024,4096]
  const float* b     = (const float*)d_in[3];
  const float* gamma = (const float*)d_in[4];
  const float* beta  = (const float*)d_in[5];
  float* out = (float*)d_out;

  // ws layout: qA 64MB | qW 4MB | 2 uint max-slots  (~68MB total)
  int8_t* qA = (int8_t*)d_ws;
  int8_t* qW = qA + (size_t)MTOT * KDIM;
  unsigned* slots = (unsigned*)(qW + (size_t)NDIM * KDIM);

  hipMemsetAsync(slots, 0, 8, stream);
  maxabs_kernel<<<2048, 256, 0, stream>>>((const float4*)x, MTOT * KDIM / 4, slots);
  maxabs_kernel<<<512, 256, 0, stream>>>((const float4*)W, NDIM * KDIM / 4, slots + 1);
  quant_kernel<<<2048, 256, 0, stream>>>((const float4*)x, (uint4*)qA,
                                         MTOT * KDIM / 16, slots);
  quant_kernel<<<512, 256, 0, stream>>>((const float4*)W, (uint4*)qW,
                                        NDIM * KDIM / 16, slots + 1);
  gemm_i8<<<dim3(NDIM / 256, MTOT / 128), 256, 0, stream>>>(qA, qW, out, resid, b,
                                                            slots, slots + 1);
  ln_kernel<<<MTOT / 4, 256, 0, stream>>>(out, gamma, beta);
}

// Round 5
// 561.848 us; speedup vs baseline: 1.0185x; 1.0185x over previous
//
#include <hip/hip_runtime.h>
#include <stdint.h>

#define MTOT  16384   // B*S
#define KDIM  4096    // INTER
#define NDIM  1024    // HID
#define CLIPV 2.5f

typedef __attribute__((ext_vector_type(4)))  int i32x4;
typedef __attribute__((ext_vector_type(16))) int i32x16;
typedef __attribute__((address_space(3))) void lvoid;
typedef __attribute__((address_space(1))) void gvoid;

#define G2L16(g, l) __builtin_amdgcn_global_load_lds((gvoid*)(g), (lvoid*)(l), 16, 0, 0)

// ---------------- max|x| reduction ------------------------------------------------
// m = max|clip(x,±2.5)| = min(max|x|, 2.5). Once any lane has seen |x| >= CLIP the
// wave's contribution is exactly CLIP -> stop reading (exact). Block-reduce ->
// ONE atomic per block.
__global__ __launch_bounds__(256) void maxabs_kernel(
    const float4* __restrict__ x, int n4, unsigned* __restrict__ slot) {
  __shared__ float red[4];
  float m = 0.f;
  const int stride = gridDim.x * blockDim.x;
  for (int i = blockIdx.x * blockDim.x + threadIdx.x; i < n4; i += stride) {
    float4 v = x[i];
    m = fmaxf(m, fmaxf(fmaxf(fabsf(v.x), fabsf(v.y)),
                       fmaxf(fabsf(v.z), fabsf(v.w))));
    if (__any(m >= CLIPV)) break;   // exact: result is CLIP regardless of the rest
  }
  m = fminf(m, CLIPV);
#pragma unroll
  for (int off = 32; off > 0; off >>= 1) m = fmaxf(m, __shfl_xor(m, off));
  if ((threadIdx.x & 63) == 0) red[threadIdx.x >> 6] = m;
  __syncthreads();
  if (threadIdx.x == 0) {
    float bm = fmaxf(fmaxf(red[0], red[1]), fmaxf(red[2], red[3]));
    atomicMax(slot, __float_as_uint(bm));
  }
}

// ---------------- symmetric int8 quantization: q = rint(clip(x)*127/m) ------------
// 64 B in / 16 B out per thread per iteration (uint4 stores).
__global__ __launch_bounds__(256) void quant_kernel(
    const float4* __restrict__ x, uint4* __restrict__ q, int n16,
    const unsigned* __restrict__ slot) {
  const float m = fminf(__uint_as_float(*slot), CLIPV);  // m = min(maxabs, clip)
  const float s = 127.0f / m;
  const int stride = gridDim.x * blockDim.x;
  for (int i = blockIdx.x * blockDim.x + threadIdx.x; i < n16; i += stride) {
    const float4* xp = x + 4 * (long)i;
    uint4 o;
    unsigned* op = (unsigned*)&o;
#pragma unroll
    for (int j = 0; j < 4; ++j) {
      float4 v = xp[j];
      int a = (int)rintf(fminf(fmaxf(v.x, -CLIPV), CLIPV) * s);
      int b = (int)rintf(fminf(fmaxf(v.y, -CLIPV), CLIPV) * s);
      int c = (int)rintf(fminf(fmaxf(v.z, -CLIPV), CLIPV) * s);
      int d = (int)rintf(fminf(fmaxf(v.w, -CLIPV), CLIPV) * s);
      op[j] = (unsigned)(a & 255) | ((unsigned)(b & 255) << 8) |
              ((unsigned)(c & 255) << 16) | ((unsigned)(d & 255) << 24);
    }
    q[i] = o;
  }
}

// ---------------- int8 GEMM: C[m][n] = S * sum_k qA[m][k]*qB[n][k] -----------------
// PROVEN core (563.6 µs session): block tile 128x256, BK=128, 2-phase
// stage->syncthreads->compute->syncthreads. 4 waves in 2x2; wave tile 64x128
// (2x4 MFMA grid of mfma_i32_32x32x32_i8). Per kk: 6 ds_read_b128 feed 8 MFMAs.
// LDS 16B slots XOR-swizzled within each 128B row: data(row,c) at row*8+(c^(row&7)).
// __launch_bounds__(256,2) -> 2 blocks/CU (48KB LDS each); the other block's waves
// cover this block's vmcnt(0)+barrier drain (m114 implicit overlap).
// NEW vs proven core:
//  (a) fused bias + residual epilogue (removes 64 MB pass from ln_kernel);
//  (b) XCD-aware tile remap: HW linear id b = blockIdx.x + 4*blockIdx.y, xcd ~ b%8.
//      ytile=b&127, xtile=b>>7 puts the 4 n-tile siblings of one A-panel at
//      b = ytile+128*{0..3}, all == ytile (mod 8) -> same XCD L2 -> A-panel
//      fetched once per XCD instead of up to 4x from HBM.
__global__ __launch_bounds__(256, 2) void gemm_i8(
    const int8_t* __restrict__ qA, const int8_t* __restrict__ qB,
    float* __restrict__ out, const float* __restrict__ resid,
    const float* __restrict__ bias,
    const unsigned* __restrict__ slot_x, const unsigned* __restrict__ slot_w) {
  __shared__ __align__(16) int8_t As[128 * 128];   // 16 KB
  __shared__ __align__(16) int8_t Bs[256 * 128];   // 32 KB

  const int t  = threadIdx.x;
  const int l  = t & 63;
  const int w  = t >> 6;
  const int wm = (w & 1) * 64;    // wave m-offset
  const int wn = (w >> 1) * 128;  // wave n-offset
  const int lr = l & 31;          // m/n index within 32-tile
  const int lh = l >> 5;          // k-chunk half

  const int b = blockIdx.x + 4 * blockIdx.y;  // HW dispatch-linear id
  const long m0 = (long)(b & 127) * 128;      // ytile
  const long n0 = (long)(b >> 7) * 256;       // xtile

  i32x16 acc[2][4] = {};

  // staging pointers: slot s covers (row=s>>3, stored col=s&7 -> data col (s&7)^(row&7))
  const int8_t* gA[4];
  const int8_t* gB[8];
#pragma unroll
  for (int j = 0; j < 4; ++j) {
    const int s = t + 256 * j, row = s >> 3, cc = (s & 7) ^ (row & 7);
    gA[j] = qA + (m0 + row) * KDIM + cc * 16;
  }
#pragma unroll
  for (int j = 0; j < 8; ++j) {
    const int s = t + 256 * j, row = s >> 3, cc = (s & 7) ^ (row & 7);
    gB[j] = qB + (n0 + row) * KDIM + cc * 16;
  }
  const int ldsb = (t & 192) * 16;  // wave-uniform: w*1024 (+ j*4096 per issue)

  // fragment address prep (per-lane): addr = base + ((kk*2+lh) ^ mask)*16
  int abase[2], amask[2], bbase[4], bmask[4];
#pragma unroll
  for (int mt = 0; mt < 2; ++mt) {
    const int ra = wm + mt * 32 + lr;
    abase[mt] = ra * 128; amask[mt] = ra & 7;
  }
#pragma unroll
  for (int nt = 0; nt < 4; ++nt) {
    const int rb = wn + nt * 32 + lr;
    bbase[nt] = rb * 128; bmask[nt] = rb & 7;
  }

  for (int k0 = 0; k0 < KDIM; k0 += 128) {
#pragma unroll
    for (int j = 0; j < 4; ++j) G2L16(gA[j] + k0, As + ldsb + j * 4096);
#pragma unroll
    for (int j = 0; j < 8; ++j) G2L16(gB[j] + k0, Bs + ldsb + j * 4096);
    __syncthreads();
#pragma unroll
    for (int kk = 0; kk < 4; ++kk) {
      const int c = kk * 2 + lh;
      i32x4 a0 = *(const i32x4*)(As + abase[0] + ((c ^ amask[0]) << 4));
      i32x4 a1 = *(const i32x4*)(As + abase[1] + ((c ^ amask[1]) << 4));
      i32x4 b0 = *(const i32x4*)(Bs + bbase[0] + ((c ^ bmask[0]) << 4));
      i32x4 b1 = *(const i32x4*)(Bs + bbase[1] + ((c ^ bmask[1]) << 4));
      i32x4 b2 = *(const i32x4*)(Bs + bbase[2] + ((c ^ bmask[2]) << 4));
      i32x4 b3 = *(const i32x4*)(Bs + bbase[3] + ((c ^ bmask[3]) << 4));
      acc[0][0] = __builtin_amdgcn_mfma_i32_32x32x32_i8(a0, b0, acc[0][0], 0, 0, 0);
      acc[1][0] = __builtin_amdgcn_mfma_i32_32x32x32_i8(a1, b0, acc[1][0], 0, 0, 0);
      acc[0][1] = __builtin_amdgcn_mfma_i32_32x32x32_i8(a0, b1, acc[0][1], 0, 0, 0);
      acc[1][1] = __builtin_amdgcn_mfma_i32_32x32x32_i8(a1, b1, acc[1][1], 0, 0, 0);
      acc[0][2] = __builtin_amdgcn_mfma_i32_32x32x32_i8(a0, b2, acc[0][2], 0, 0, 0);
      acc[1][2] = __builtin_amdgcn_mfma_i32_32x32x32_i8(a1, b2, acc[1][2], 0, 0, 0);
      acc[0][3] = __builtin_amdgcn_mfma_i32_32x32x32_i8(a0, b3, acc[0][3], 0, 0, 0);
      acc[1][3] = __builtin_amdgcn_mfma_i32_32x32x32_i8(a1, b3, acc[1][3], 0, 0, 0);
    }
    __syncthreads();
  }

  const float mx = fminf(__uint_as_float(*slot_x), CLIPV);
  const float mw = fminf(__uint_as_float(*slot_w), CLIPV);
  const float S  = mx * mw * (1.0f / (127.0f * 127.0f));

  // C/D layout (32x32, dtype-independent): col=lane&31, row=(r&3)+8*(r>>2)+4*(lane>>5)
  const int coln = (int)n0 + wn + lr;
  float bv[4];
#pragma unroll
  for (int nt = 0; nt < 4; ++nt) bv[nt] = bias[coln + nt * 32];

#pragma unroll
  for (int mt = 0; mt < 2; ++mt)
#pragma unroll
    for (int r = 0; r < 16; ++r) {
      const long row = m0 + wm + mt * 32 + (r & 3) + 8 * (r >> 2) + 4 * lh;
      float* orow = out + row * NDIM + coln;
      const float* rrow = resid + row * NDIM + coln;
#pragma unroll
      for (int nt = 0; nt < 4; ++nt)
        orow[nt * 32] = (float)acc[mt][nt][r] * S + bv[nt] + rrow[nt * 32];
    }
}

// ---------------- LayerNorm (in-place on y = h + b + resid) ------------------------
// One wave per row; each lane covers 4 float4s (lane + 64*j -> 1024 floats/row).
// No LDS, no __syncthreads.
__global__ __launch_bounds__(256) void ln_kernel(
    float* __restrict__ h, const float* __restrict__ gamma,
    const float* __restrict__ beta) {
  const int lane = threadIdx.x & 63;
  const long row = (long)blockIdx.x * 4 + (threadIdx.x >> 6);
  float4* hp = (float4*)(h + row * NDIM);
  float4 y[4];
  float sum = 0.f, ss = 0.f;
#pragma unroll
  for (int j = 0; j < 4; ++j) {
    y[j] = hp[lane + 64 * j];
    sum += y[j].x + y[j].y + y[j].z + y[j].w;
    ss  += y[j].x * y[j].x + y[j].y * y[j].y + y[j].z * y[j].z + y[j].w * y[j].w;
  }
#pragma unroll
  for (int off = 32; off > 0; off >>= 1) {
    sum += __shfl_xor(sum, off);
    ss  += __shfl_xor(ss, off);
  }
  const float mu   = sum * (1.0f / NDIM);
  const float var  = ss * (1.0f / NDIM) - mu * mu;
  const float rstd = rsqrtf(var + 1e-12f);
#pragma unroll
  for (int j = 0; j < 4; ++j) {
    float4 g  = ((const float4*)gamma)[lane + 64 * j];
    float4 be = ((const float4*)beta)[lane + 64 * j];
    float4 o;
    o.x = g.x * (y[j].x - mu) * rstd + be.x;
    o.y = g.y * (y[j].y - mu) * rstd + be.y;
    o.z = g.z * (y[j].z - mu) * rstd + be.z;
    o.w = g.w * (y[j].w - mu) * rstd + be.w;
    hp[lane + 64 * j] = o;
  }
}

extern "C" void kernel_launch(void* const* d_in, const int* in_sizes, int n_in,
                              void* d_out, int out_size, void* d_ws,
                              size_t ws_size, hipStream_t stream) {
  const float* x     = (const float*)d_in[0];  // hidden_states [4,4096,4096]
  const float* resid = (const float*)d_in[1];  // input_tensor  [4,4096,1024]
  const float* W     = (const float*)d_in[2];  // [1024,4096]
  const float* b     = (const float*)d_in[3];
  const float* gamma = (const float*)d_in[4];
  const float* beta  = (const float*)d_in[5];
  float* out = (float*)d_out;

  // ws layout: qA 64MB | qW 4MB | 2 uint max-slots  (~68MB total)
  int8_t* qA = (int8_t*)d_ws;
  int8_t* qW = qA + (size_t)MTOT * KDIM;
  unsigned* slots = (unsigned*)(qW + (size_t)NDIM * KDIM);

  hipMemsetAsync(slots, 0, 8, stream);
  maxabs_kernel<<<2048, 256, 0, stream>>>((const float4*)x, MTOT * KDIM / 4, slots);
  maxabs_kernel<<<512, 256, 0, stream>>>((const float4*)W, NDIM * KDIM / 4, slots + 1);
  quant_kernel<<<2048, 256, 0, stream>>>((const float4*)x, (uint4*)qA,
                                         MTOT * KDIM / 16, slots);
  quant_kernel<<<512, 256, 0, stream>>>((const float4*)W, (uint4*)qW,
                                        NDIM * KDIM / 16, slots + 1);
  gemm_i8<<<dim3(NDIM / 256, MTOT / 128), 256, 0, stream>>>(qA, qW, out, resid, b,
                                                            slots, slots + 1);
  ln_kernel<<<MTOT / 4, 256, 0, stream>>>(out, gamma, beta);
}